// Round 4
// baseline (801.247 us; speedup 1.0000x reference)
//
#include <hip/hip_runtime.h>

#define HIDDEN 128
#define TSTEPS 512
#define NFUT 50
#define BR 8           // batch rows per block -> grid 512 = 2 blocks/CU (async dephase)
#define THREADS 512    // 8 waves/block; 2 blocks/CU -> 4 waves/SIMD
#define HPITCH 136     // h row pitch in bf16 (272B rows: 16B-aligned for b128)

typedef __bf16 bf16x8 __attribute__((ext_vector_type(8)));
typedef float floatx4 __attribute__((ext_vector_type(4)));
typedef float f32x2 __attribute__((ext_vector_type(2)));

union B8 { int4 i; bf16x8 v; };

#if defined(__has_builtin)
#  if __has_builtin(__builtin_amdgcn_exp2f)
#    define EXP2F(x) __builtin_amdgcn_exp2f(x)
#  else
#    define EXP2F(x) exp2f(x)
#  endif
#  if __has_builtin(__builtin_amdgcn_rcpf)
#    define RCPF(x) __builtin_amdgcn_rcpf(x)
#  else
#    define RCPF(x) (1.0f / (x))
#  endif
#  if __has_builtin(__builtin_amdgcn_s_setprio)
#    define SETPRIO(p) __builtin_amdgcn_s_setprio(p)
#  else
#    define SETPRIO(p)
#  endif
#else
#  define EXP2F(x) exp2f(x)
#  define RCPF(x) (1.0f / (x))
#  define SETPRIO(p)
#endif

#define L2E  1.4426950408889634f
#define L2E2 2.8853900817779268f

__global__ __launch_bounds__(THREADS, 4)
void lstm_forecast_kernel(const float* __restrict__ x,
                          const float* __restrict__ W_ih,
                          const float* __restrict__ W_hh,
                          const float* __restrict__ b_ih,
                          const float* __restrict__ b_hh,
                          const float* __restrict__ fc_w,
                          const float* __restrict__ fc_b,
                          float* __restrict__ out) {
    // LDS: xa 32KB + h 8.5KB + fcw 1KB ~= 42KB -> 2 blocks/CU (84KB of 160KB)
    __shared__ __align__(16) uint2  xa[TSTEPS * BR];        // (x0h,x1h),(x0r,x1r) bf16 splits
    __shared__ __align__(16) __bf16 h_lds[2][16 * HPITCH];  // 16 rows for MFMA B; rows 8-15 stay 0
    __shared__ __align__(16) float  fcw_lds[2][HIDDEN];

    const int tid  = threadIdx.x;
    const int wave = tid >> 6;          // 0..7
    const int lane = tid & 63;
    const int quad = lane >> 4;
    const int l15  = lane & 15;
    const int hi8  = (lane >> 3) & 1;   // l15 >= 8: this lane ews cols cbase+2,3 of row l15-8
    const int row8 = lane & 7;          // real batch row this lane ews / reads x for
    const int rb   = blockIdx.x * BR;

    if (tid < 256) fcw_lds[tid >> 7][tid & 127] = fc_w[tid];

    // ---- stage x as bf16 hi/lo splits: xa[t][row] (feeds the x-MFMA) ----
    {
        const int row = tid & 7;
        for (int tb = tid >> 3; tb < TSTEPS; tb += THREADS >> 3) {
            float2 xv = *(const float2*)&x[(size_t)(rb + row) * (2 * TSTEPS) + tb * 2];
            __bf16 x0h = (__bf16)xv.x, x1h = (__bf16)xv.y;
            __bf16 x0r = (__bf16)(xv.x - (float)x0h);
            __bf16 x1r = (__bf16)(xv.y - (float)x1h);
            uint2 d;
            d.x = (unsigned)__builtin_bit_cast(unsigned short, x0h) |
                  ((unsigned)__builtin_bit_cast(unsigned short, x1h) << 16);
            d.y = (unsigned)__builtin_bit_cast(unsigned short, x0r) |
                  ((unsigned)__builtin_bit_cast(unsigned short, x1r) << 16);
            xa[tb * BR + row] = d;
        }
    }
    // zero both h buffers fully: rows 8-15 are never written and must stay 0
    for (int i = tid; i < 2 * 16 * HPITCH; i += THREADS) (&h_lds[0][0])[i] = (__bf16)0.0f;

    // ---- weights -> registers, pre-scaled so MFMA outputs are exp2-ready ----
    // gate scale: i,f,o -> -log2(e); g -> -2*log2(e)
    // Transposed MFMA: bfrag/bfx = A operand (m = gate col = wave*16 + l15),
    // h/x = B operand (n = batch row = l15; rows 8-15 are zero padding).
    // C layout: n(=lane&15) = batch row, m(=quad*4+reg) = gate-col offset.
    bf16x8 bfrag[4][4];   // [gate][kchunk] scaled W_hh (later W_eff)
    B8 bfx[4];            // scaled W_ih + bias hi/lo, quad0 k-slots only (A operand)
    float gs[4];
    const float fcb0 = fc_b[0], fcb1 = fc_b[1];
    const int ub    = wave * 16 + l15;        // A-layout gate col (weights)
    const int cbase = wave * 16 + quad * 4;   // C-layout gate-col base (ew/h-write)
#pragma unroll
    for (int g = 0; g < 4; ++g) {
        gs[g] = (g == 2) ? -L2E2 : -L2E;
        const int cg = g * HIDDEN + ub;
        const float w0 = W_ih[cg * 2 + 0];
        const float w1 = W_ih[cg * 2 + 1];
        const float bs = b_ih[cg] + b_hh[cg];
#pragma unroll
        for (int ks = 0; ks < 4; ++ks) {
            const float* wp = W_hh + (size_t)cg * HIDDEN + ks * 32 + quad * 8;
            bf16x8 bb;
#pragma unroll
            for (int j = 0; j < 8; ++j) bb[j] = (__bf16)(gs[g] * wp[j]);
            bfrag[g][ks] = bb;
        }
        B8 t; t.i = make_int4(0, 0, 0, 0);
        if (quad == 0) {
            const float w0s = gs[g] * w0, w1s = gs[g] * w1, bss = gs[g] * bs;
            __bf16 w0h = (__bf16)w0s, w1h = (__bf16)w1s;
            __bf16 w0l = (__bf16)(w0s - (float)w0h);
            __bf16 w1l = (__bf16)(w1s - (float)w1h);
            __bf16 bh  = (__bf16)bss;
            __bf16 bl  = (__bf16)(bss - (float)bh);
            bf16x8 bv = {w0h, w1h, bh, bl, w0h, w1h, w0l, w1l};
            t.v = bv;
        }
        bfx[g] = t;
    }

    const unsigned ones2 = 0x3F803F80u;  // bf16(1.0) x2
    const int hrow = l15 * HPITCH;       // B-operand read row (0..15; 8-15 are zeros)
    f32x2 cst = {0.f, 0.f};              // ONE pair of cells per thread now

    auto mk = [](float a, float b) { f32x2 r; r.x = a; r.y = b; return r; };
    auto pk2 = [](f32x2 hn) -> unsigned {
        return (unsigned)__builtin_bit_cast(unsigned short, (__bf16)hn.x)
             | ((unsigned)__builtin_bit_cast(unsigned short, (__bf16)hn.y) << 16);
    };

    // ew for this thread's single cell-pair: 10 exp + 2 batched rcp
    auto ewPair = [&](f32x2 gi, f32x2 gf, f32x2 gg, f32x2 go) -> unsigned {
        f32x2 ea, ec, eb, eo;
        ea.x = EXP2F(gi.x); ea.y = EXP2F(gi.y);   // e^-i
        ec.x = EXP2F(gf.x); ec.y = EXP2F(gf.y);   // e^-f
        eb.x = EXP2F(gg.x); eb.y = EXP2F(gg.y);   // e^-2g
        eo.x = EXP2F(go.x); eo.y = EXP2F(go.y);   // e^-o
        const f32x2 A1 = 1.f + ea, B1 = 1.f + eb, C1 = 1.f + ec;
        const f32x2 P  = A1 * B1;
        const f32x2 PC = P * C1;
        f32x2 R;                                  // batched: 1 rcp for the pair
        { const float I = RCPF(PC.x * PC.y); R.x = I * PC.y; R.y = I * PC.x; }
        const f32x2 sfv = P * R;                  // sigmoid(f)
        const f32x2 igv = (1.f - eb) * (C1 * R);  // sigmoid(i)*tanh(g)
        const f32x2 cn  = sfv * cst + igv;
        cst = cn;
        const f32x2 am = -L2E2 * cn;
        f32x2 ed;
        ed.x = EXP2F(fminf(am.x, 29.f));          // c clamped at -10 (tanh err < 4e-9)
        ed.y = EXP2F(fminf(am.y, 29.f));
        const f32x2 E = (1.f + ed) * (1.f + eo);
        f32x2 R2;                                 // batched: 1 rcp for the pair
        { const float J = RCPF(E.x * E.y); R2.x = J * E.y; R2.y = J * E.x; }
        const f32x2 hn = (1.f - ed) * R2;         // sigmoid(o)*tanh(c)
        return pk2(hn);
    };

    // post-MFMA: redistribute (hi half-lanes take acc[2],[3] of lane-8) + ew + b32 write.
    // Shuffle is AFTER accumulation -> exact f32, bias/x-init untouched.
    auto finish = [&](floatx4 a0, floatx4 a1, floatx4 a2, floatx4 a3, __bf16* hd) {
        const int src = lane & ~8;
        float s2[4], s3[4];
        s2[0] = __shfl(a0[2], src); s3[0] = __shfl(a0[3], src);
        s2[1] = __shfl(a1[2], src); s3[1] = __shfl(a1[3], src);
        s2[2] = __shfl(a2[2], src); s3[2] = __shfl(a2[3], src);
        s2[3] = __shfl(a3[2], src); s3[3] = __shfl(a3[3], src);
        const f32x2 gi = hi8 ? mk(s2[0], s3[0]) : mk(a0[0], a0[1]);
        const f32x2 gf = hi8 ? mk(s2[1], s3[1]) : mk(a1[0], a1[1]);
        const f32x2 gg = hi8 ? mk(s2[2], s3[2]) : mk(a2[0], a2[1]);
        const f32x2 go = hi8 ? mk(s2[3], s3[3]) : mk(a3[0], a3[1]);
        const unsigned pkd = ewPair(gi, gf, gg, go);
        // row row8, cols cbase+hi8*2 .. +1 : 64 lanes -> 2 per bank, conflict-free
        *(unsigned*)&hd[row8 * HPITCH + cbase + hi8 * 2] = pkd;
    };

    // Encode cell: x+bias via MFMA on the underused matrix pipe; ks-outer/g-inner
    // = 4 independent accumulation chains. Prefetch next xa under ew+barrier.
    auto cellE = [&](const __bf16* hs, __bf16* hd, uint2 xd, int tn) -> uint2 {
        B8 xf; xf.i = make_int4((int)xd.x, (int)ones2, (int)xd.y, (int)xd.x);
        bf16x8 af[4];
#pragma unroll
        for (int ks = 0; ks < 4; ++ks)
            af[ks] = *(const bf16x8*)&hs[hrow + ks * 32 + quad * 8];
        const floatx4 z = {0.f, 0.f, 0.f, 0.f};
        floatx4 acc[4];
        SETPRIO(1);
#pragma unroll
        for (int g = 0; g < 4; ++g)
            acc[g] = __builtin_amdgcn_mfma_f32_16x16x32_bf16(bfx[g].v, xf.v, z, 0, 0, 0);
#pragma unroll
        for (int ks = 0; ks < 4; ++ks)
#pragma unroll
            for (int g = 0; g < 4; ++g)
                acc[g] = __builtin_amdgcn_mfma_f32_16x16x32_bf16(bfrag[g][ks], af[ks], acc[g], 0, 0, 0);
        SETPRIO(0);
        const int ts = (tn < TSTEPS) ? tn : 0;
        const uint2 xn = xa[ts * BR + row8];                // prefetch (consumed next cell)
        finish(acc[0], acc[1], acc[2], acc[3], hd);
        __syncthreads();
        return xn;
    };

    __syncthreads();

    // ================= encode: 512 steps =================
    uint2 xd = xa[row8];                                    // t = 0
    for (int t = 0; t < TSTEPS; t += 2) {
        xd = cellE(h_lds[0], h_lds[1], xd, t + 1);
        xd = cellE(h_lds[1], h_lds[0], xd, t + 2);
    }

    // ========== transition: fold fc into weights =========
    // W_eff = gs*(W_hh + W_ih*fc_w) (A-layout fold); b_eff exact fp32 in C-layout
    // (beff identical across a shuffle pair: depends only on cbase -> shuffle-safe).
    floatx4 beff[4];
#pragma unroll
    for (int g = 0; g < 4; ++g) {
        const int cgA = g * HIDDEN + ub;
        const float wi0 = W_ih[cgA * 2 + 0];
        const float wi1 = W_ih[cgA * 2 + 1];
#pragma unroll
        for (int ks = 0; ks < 4; ++ks) {
            const int k0 = ks * 32 + quad * 8;
            bf16x8 bb = bfrag[g][ks];
#pragma unroll
            for (int j = 0; j < 8; ++j)
                bb[j] = (__bf16)((float)bb[j] + gs[g] * (wi0 * fcw_lds[0][k0 + j]
                                                       + wi1 * fcw_lds[1][k0 + j]));
            bfrag[g][ks] = bb;
        }
        floatx4 v;
#pragma unroll
        for (int r = 0; r < 4; ++r) {
            const int cg = g * HIDDEN + cbase + r;          // C-layout col
            v[r] = gs[g] * (b_ih[cg] + b_hh[cg]
                          + W_ih[cg * 2 + 0] * fcb0 + W_ih[cg * 2 + 1] * fcb1);
        }
        beff[g] = v;
    }

    auto cellF = [&](const __bf16* hs, __bf16* hd) {
        bf16x8 af[4];
#pragma unroll
        for (int ks = 0; ks < 4; ++ks)
            af[ks] = *(const bf16x8*)&hs[hrow + ks * 32 + quad * 8];
        floatx4 acc[4];
#pragma unroll
        for (int g = 0; g < 4; ++g) acc[g] = beff[g];       // exact fp32 scaled bias
        SETPRIO(1);
#pragma unroll
        for (int ks = 0; ks < 4; ++ks)
#pragma unroll
            for (int g = 0; g < 4; ++g)
                acc[g] = __builtin_amdgcn_mfma_f32_16x16x32_bf16(bfrag[g][ks], af[ks], acc[g], 0, 0, 0);
        SETPRIO(0);
        finish(acc[0], acc[1], acc[2], acc[3], hd);
        __syncthreads();
    };

    // y output only (no feedback): wave0 computes while others run MFMA
    auto emitY = [&](const __bf16* hs, int f) {
        if (wave == 0) {
            const int r = lane & 7, seg = lane >> 3;        // 8 segs x 16 cols
            const __bf16* hp = &hs[r * HPITCH + seg * 16];
            float p0 = 0.f, p1 = 0.f;
#pragma unroll
            for (int js = 0; js < 2; ++js) {
                bf16x8 hv = *(const bf16x8*)&hp[js * 8];
                const float4* f0 = (const float4*)&fcw_lds[0][seg * 16 + js * 8];
                const float4* f1 = (const float4*)&fcw_lds[1][seg * 16 + js * 8];
                float4 a0 = f0[0], b0 = f0[1], a1 = f1[0], b1 = f1[1];
                p0 += (float)hv[0]*a0.x + (float)hv[1]*a0.y + (float)hv[2]*a0.z + (float)hv[3]*a0.w
                    + (float)hv[4]*b0.x + (float)hv[5]*b0.y + (float)hv[6]*b0.z + (float)hv[7]*b0.w;
                p1 += (float)hv[0]*a1.x + (float)hv[1]*a1.y + (float)hv[2]*a1.z + (float)hv[3]*a1.w
                    + (float)hv[4]*b1.x + (float)hv[5]*b1.y + (float)hv[6]*b1.z + (float)hv[7]*b1.w;
            }
            p0 += __shfl_xor(p0, 8); p0 += __shfl_xor(p0, 16); p0 += __shfl_xor(p0, 32);
            p1 += __shfl_xor(p1, 8); p1 += __shfl_xor(p1, 16); p1 += __shfl_xor(p1, 32);
            if (seg == 0) {
                float* op = &out[(size_t)(rb + r) * (2 * NFUT) + f * 2];
                op[0] = p0 + fcb0;
                op[1] = p1 + fcb1;
            }
        }
    };

    // ================= forecast: 50 steps ================
    for (int f = 0; f < NFUT; f += 2) {
        emitY(h_lds[0], f);
        cellF(h_lds[0], h_lds[1]);
        emitY(h_lds[1], f + 1);
        cellF(h_lds[1], h_lds[0]);
    }
}

extern "C" void kernel_launch(void* const* d_in, const int* in_sizes, int n_in,
                              void* d_out, int out_size, void* d_ws, size_t ws_size,
                              hipStream_t stream) {
    const float* x    = (const float*)d_in[0];
    const float* W_ih = (const float*)d_in[1];
    const float* W_hh = (const float*)d_in[2];
    const float* b_ih = (const float*)d_in[3];
    const float* b_hh = (const float*)d_in[4];
    const float* fc_w = (const float*)d_in[5];
    const float* fc_b = (const float*)d_in[6];
    float* out = (float*)d_out;

    const int B = in_sizes[0] / (TSTEPS * 2);   // 4096
    const int grid = B / BR;                    // 512 blocks -> 2 per CU
    lstm_forecast_kernel<<<grid, THREADS, 0, stream>>>(x, W_ih, W_hh, b_ih, b_hh, fc_w, fc_b, out);
}

// Round 6
// 765.750 us; speedup vs baseline: 1.0464x; 1.0464x over previous
//
#include <hip/hip_runtime.h>

#define HIDDEN 128
#define TSTEPS 512
#define NFUT 50
#define BR 8           // batch rows per block -> grid 512 = 2 blocks/CU (async dephase)
#define THREADS 512    // 8 waves/block; 2 blocks/CU -> 4 waves/SIMD
#define HPITCH 136     // h row pitch in bf16 (272B rows: 16B-aligned for b128)

typedef __bf16 bf16x8 __attribute__((ext_vector_type(8)));
typedef float floatx4 __attribute__((ext_vector_type(4)));
typedef float f32x2 __attribute__((ext_vector_type(2)));

union B8 { int4 i; bf16x8 v; };

#if defined(__has_builtin)
#  if __has_builtin(__builtin_amdgcn_exp2f)
#    define EXP2F(x) __builtin_amdgcn_exp2f(x)
#  else
#    define EXP2F(x) exp2f(x)
#  endif
#  if __has_builtin(__builtin_amdgcn_rcpf)
#    define RCPF(x) __builtin_amdgcn_rcpf(x)
#  else
#    define RCPF(x) (1.0f / (x))
#  endif
#  if __has_builtin(__builtin_amdgcn_s_setprio)
#    define SETPRIO(p) __builtin_amdgcn_s_setprio(p)
#  else
#    define SETPRIO(p)
#  endif
#else
#  define EXP2F(x) exp2f(x)
#  define RCPF(x) (1.0f / (x))
#  define SETPRIO(p)
#endif

#define L2E  1.4426950408889634f
#define L2E2 2.8853900817779268f

// (THREADS, 2): HIP treats arg2 as min waves/EU; at 512 threads this equals
// blocks/CU. R4 evidence: (,4) -> VGPR cap 64 -> spill storm (266MB scratch
// traffic, dur == bytes/BW). (,2) -> cap 128; R3-identical footprint compiled
// to 92 VGPRs. 2 blocks/CU is exactly the residency we want for dephasing.
__global__ __launch_bounds__(THREADS, 2)
void lstm_forecast_kernel(const float* __restrict__ x,
                          const float* __restrict__ W_ih,
                          const float* __restrict__ W_hh,
                          const float* __restrict__ b_ih,
                          const float* __restrict__ b_hh,
                          const float* __restrict__ fc_w,
                          const float* __restrict__ fc_b,
                          float* __restrict__ out) {
    // LDS: xa 32KB + h 8.7KB + fcw 1KB ~= 42KB -> 2 blocks/CU (85KB of 160KB)
    __shared__ __align__(16) uint2  xa[TSTEPS * BR];        // (x0h,x1h),(x0r,x1r) bf16 splits
    __shared__ __align__(16) __bf16 h_lds[2][16 * HPITCH];  // 16 rows for MFMA B; rows 8-15 stay 0
    __shared__ __align__(16) float  fcw_lds[2][HIDDEN];

    const int tid  = threadIdx.x;
    const int wave = tid >> 6;          // 0..7
    const int lane = tid & 63;
    const int quad = lane >> 4;
    const int l15  = lane & 15;
    const int hi8  = (lane >> 3) & 1;   // l15 >= 8: this lane ews cols cbase+2,3 of row l15-8
    const int row8 = lane & 7;          // real batch row this lane ews / reads x for
    const int rb   = blockIdx.x * BR;

    if (tid < 256) fcw_lds[tid >> 7][tid & 127] = fc_w[tid];

    // ---- stage x as bf16 hi/lo splits: xa[t][row] (feeds the x-MFMA) ----
    {
        const int row = tid & 7;
        for (int tb = tid >> 3; tb < TSTEPS; tb += THREADS >> 3) {
            float2 xv = *(const float2*)&x[(size_t)(rb + row) * (2 * TSTEPS) + tb * 2];
            __bf16 x0h = (__bf16)xv.x, x1h = (__bf16)xv.y;
            __bf16 x0r = (__bf16)(xv.x - (float)x0h);
            __bf16 x1r = (__bf16)(xv.y - (float)x1h);
            uint2 d;
            d.x = (unsigned)__builtin_bit_cast(unsigned short, x0h) |
                  ((unsigned)__builtin_bit_cast(unsigned short, x1h) << 16);
            d.y = (unsigned)__builtin_bit_cast(unsigned short, x0r) |
                  ((unsigned)__builtin_bit_cast(unsigned short, x1r) << 16);
            xa[tb * BR + row] = d;
        }
    }
    // zero both h buffers fully: rows 8-15 are never written and must stay 0
    for (int i = tid; i < 2 * 16 * HPITCH; i += THREADS) (&h_lds[0][0])[i] = (__bf16)0.0f;

    // ---- weights -> registers, pre-scaled so MFMA outputs are exp2-ready ----
    // gate scale: i,f,o -> -log2(e); g -> -2*log2(e)
    // Transposed MFMA: bfrag/bfx = A operand (m = gate col = wave*16 + l15),
    // h/x = B operand (n = batch row = l15; rows 8-15 are zero padding).
    // C layout: n(=lane&15) = batch row, m(=quad*4+reg) = gate-col offset.
    bf16x8 bfrag[4][4];   // [gate][kchunk] scaled W_hh (later W_eff)
    B8 bfx[4];            // scaled W_ih + bias hi/lo, quad0 k-slots only (A operand)
    float gs[4];
    const float fcb0 = fc_b[0], fcb1 = fc_b[1];
    const int ub    = wave * 16 + l15;        // A-layout gate col (weights)
    const int cbase = wave * 16 + quad * 4;   // C-layout gate-col base (ew/h-write)
#pragma unroll
    for (int g = 0; g < 4; ++g) {
        gs[g] = (g == 2) ? -L2E2 : -L2E;
        const int cg = g * HIDDEN + ub;
        const float w0 = W_ih[cg * 2 + 0];
        const float w1 = W_ih[cg * 2 + 1];
        const float bs = b_ih[cg] + b_hh[cg];
#pragma unroll
        for (int ks = 0; ks < 4; ++ks) {
            const float* wp = W_hh + (size_t)cg * HIDDEN + ks * 32 + quad * 8;
            bf16x8 bb;
#pragma unroll
            for (int j = 0; j < 8; ++j) bb[j] = (__bf16)(gs[g] * wp[j]);
            bfrag[g][ks] = bb;
        }
        B8 t; t.i = make_int4(0, 0, 0, 0);
        if (quad == 0) {
            const float w0s = gs[g] * w0, w1s = gs[g] * w1, bss = gs[g] * bs;
            __bf16 w0h = (__bf16)w0s, w1h = (__bf16)w1s;
            __bf16 w0l = (__bf16)(w0s - (float)w0h);
            __bf16 w1l = (__bf16)(w1s - (float)w1h);
            __bf16 bh  = (__bf16)bss;
            __bf16 bl  = (__bf16)(bss - (float)bh);
            bf16x8 bv = {w0h, w1h, bh, bl, w0h, w1h, w0l, w1l};
            t.v = bv;
        }
        bfx[g] = t;
    }

    const unsigned ones2 = 0x3F803F80u;  // bf16(1.0) x2
    const int hrow = l15 * HPITCH;       // B-operand read row (0..15; 8-15 are zeros)
    f32x2 cst = {0.f, 0.f};              // ONE pair of cells per thread

    auto mk = [](float a, float b) { f32x2 r; r.x = a; r.y = b; return r; };
    auto pk2 = [](f32x2 hn) -> unsigned {
        return (unsigned)__builtin_bit_cast(unsigned short, (__bf16)hn.x)
             | ((unsigned)__builtin_bit_cast(unsigned short, (__bf16)hn.y) << 16);
    };

    // ew for this thread's single cell-pair: 10 exp + 2 batched rcp
    auto ewPair = [&](f32x2 gi, f32x2 gf, f32x2 gg, f32x2 go) -> unsigned {
        f32x2 ea, ec, eb, eo;
        ea.x = EXP2F(gi.x); ea.y = EXP2F(gi.y);   // e^-i
        ec.x = EXP2F(gf.x); ec.y = EXP2F(gf.y);   // e^-f
        eb.x = EXP2F(gg.x); eb.y = EXP2F(gg.y);   // e^-2g
        eo.x = EXP2F(go.x); eo.y = EXP2F(go.y);   // e^-o
        const f32x2 A1 = 1.f + ea, B1 = 1.f + eb, C1 = 1.f + ec;
        const f32x2 P  = A1 * B1;
        const f32x2 PC = P * C1;
        f32x2 R;                                  // batched: 1 rcp for the pair
        { const float I = RCPF(PC.x * PC.y); R.x = I * PC.y; R.y = I * PC.x; }
        const f32x2 sfv = P * R;                  // sigmoid(f)
        const f32x2 igv = (1.f - eb) * (C1 * R);  // sigmoid(i)*tanh(g)
        const f32x2 cn  = sfv * cst + igv;
        cst = cn;
        const f32x2 am = -L2E2 * cn;
        f32x2 ed;
        ed.x = EXP2F(fminf(am.x, 29.f));          // c clamped at -10 (tanh err < 4e-9)
        ed.y = EXP2F(fminf(am.y, 29.f));
        const f32x2 E = (1.f + ed) * (1.f + eo);
        f32x2 R2;                                 // batched: 1 rcp for the pair
        { const float J = RCPF(E.x * E.y); R2.x = J * E.y; R2.y = J * E.x; }
        const f32x2 hn = (1.f - ed) * R2;         // sigmoid(o)*tanh(c)
        return pk2(hn);
    };

    // post-MFMA: redistribute (hi half-lanes take acc[2],[3] from lane^8 = lane-8)
    // + ew + b32 write. Shuffle AFTER accumulation -> exact f32; xor-shuffle is a
    // single ds_swizzle. Lo lanes' incoming (hi-lane) values are simply unused.
    auto finish = [&](floatx4 a0, floatx4 a1, floatx4 a2, floatx4 a3, __bf16* hd) {
        const float s20 = __shfl_xor(a0[2], 8), s30 = __shfl_xor(a0[3], 8);
        const float s21 = __shfl_xor(a1[2], 8), s31 = __shfl_xor(a1[3], 8);
        const float s22 = __shfl_xor(a2[2], 8), s32 = __shfl_xor(a2[3], 8);
        const float s23 = __shfl_xor(a3[2], 8), s33 = __shfl_xor(a3[3], 8);
        const f32x2 gi = hi8 ? mk(s20, s30) : mk(a0[0], a0[1]);
        const f32x2 gf = hi8 ? mk(s21, s31) : mk(a1[0], a1[1]);
        const f32x2 gg = hi8 ? mk(s22, s32) : mk(a2[0], a2[1]);
        const f32x2 go = hi8 ? mk(s23, s33) : mk(a3[0], a3[1]);
        const unsigned pkd = ewPair(gi, gf, gg, go);
        // row row8, cols cbase+hi8*2 .. +1 : 64 lanes -> 2 per bank, conflict-free
        *(unsigned*)&hd[row8 * HPITCH + cbase + hi8 * 2] = pkd;
    };

    // Encode cell: x+bias via MFMA on the underused matrix pipe; ks-outer/g-inner
    // = 4 independent accumulation chains. Prefetch next xa under ew+barrier.
    auto cellE = [&](const __bf16* hs, __bf16* hd, uint2 xd, int tn) -> uint2 {
        B8 xf; xf.i = make_int4((int)xd.x, (int)ones2, (int)xd.y, (int)xd.x);
        bf16x8 af[4];
#pragma unroll
        for (int ks = 0; ks < 4; ++ks)
            af[ks] = *(const bf16x8*)&hs[hrow + ks * 32 + quad * 8];
        const floatx4 z = {0.f, 0.f, 0.f, 0.f};
        floatx4 acc[4];
        SETPRIO(1);
#pragma unroll
        for (int g = 0; g < 4; ++g)
            acc[g] = __builtin_amdgcn_mfma_f32_16x16x32_bf16(bfx[g].v, xf.v, z, 0, 0, 0);
#pragma unroll
        for (int ks = 0; ks < 4; ++ks)
#pragma unroll
            for (int g = 0; g < 4; ++g)
                acc[g] = __builtin_amdgcn_mfma_f32_16x16x32_bf16(bfrag[g][ks], af[ks], acc[g], 0, 0, 0);
        SETPRIO(0);
        const int ts = (tn < TSTEPS) ? tn : 0;
        const uint2 xn = xa[ts * BR + row8];                // prefetch (consumed next cell)
        finish(acc[0], acc[1], acc[2], acc[3], hd);
        __syncthreads();
        return xn;
    };

    __syncthreads();

    // ================= encode: 512 steps =================
    uint2 xd = xa[row8];                                    // t = 0
    for (int t = 0; t < TSTEPS; t += 2) {
        xd = cellE(h_lds[0], h_lds[1], xd, t + 1);
        xd = cellE(h_lds[1], h_lds[0], xd, t + 2);
    }

    // ========== transition: fold fc into weights =========
    // W_eff = gs*(W_hh + W_ih*fc_w) (A-layout fold); b_eff exact fp32 in C-layout
    // (beff identical across a shuffle pair: depends only on cbase -> shuffle-safe).
    floatx4 beff[4];
#pragma unroll
    for (int g = 0; g < 4; ++g) {
        const int cgA = g * HIDDEN + ub;
        const float wi0 = W_ih[cgA * 2 + 0];
        const float wi1 = W_ih[cgA * 2 + 1];
#pragma unroll
        for (int ks = 0; ks < 4; ++ks) {
            const int k0 = ks * 32 + quad * 8;
            bf16x8 bb = bfrag[g][ks];
#pragma unroll
            for (int j = 0; j < 8; ++j)
                bb[j] = (__bf16)((float)bb[j] + gs[g] * (wi0 * fcw_lds[0][k0 + j]
                                                       + wi1 * fcw_lds[1][k0 + j]));
            bfrag[g][ks] = bb;
        }
        floatx4 v;
#pragma unroll
        for (int r = 0; r < 4; ++r) {
            const int cg = g * HIDDEN + cbase + r;          // C-layout col
            v[r] = gs[g] * (b_ih[cg] + b_hh[cg]
                          + W_ih[cg * 2 + 0] * fcb0 + W_ih[cg * 2 + 1] * fcb1);
        }
        beff[g] = v;
    }

    auto cellF = [&](const __bf16* hs, __bf16* hd) {
        bf16x8 af[4];
#pragma unroll
        for (int ks = 0; ks < 4; ++ks)
            af[ks] = *(const bf16x8*)&hs[hrow + ks * 32 + quad * 8];
        floatx4 acc[4];
#pragma unroll
        for (int g = 0; g < 4; ++g) acc[g] = beff[g];       // exact fp32 scaled bias
        SETPRIO(1);
#pragma unroll
        for (int ks = 0; ks < 4; ++ks)
#pragma unroll
            for (int g = 0; g < 4; ++g)
                acc[g] = __builtin_amdgcn_mfma_f32_16x16x32_bf16(bfrag[g][ks], af[ks], acc[g], 0, 0, 0);
        SETPRIO(0);
        finish(acc[0], acc[1], acc[2], acc[3], hd);
        __syncthreads();
    };

    // y output only (no feedback): wave0 computes while others run MFMA
    auto emitY = [&](const __bf16* hs, int f) {
        if (wave == 0) {
            const int r = lane & 7, seg = lane >> 3;        // 8 segs x 16 cols
            const __bf16* hp = &hs[r * HPITCH + seg * 16];
            float p0 = 0.f, p1 = 0.f;
#pragma unroll
            for (int js = 0; js < 2; ++js) {
                bf16x8 hv = *(const bf16x8*)&hp[js * 8];
                const float4* f0 = (const float4*)&fcw_lds[0][seg * 16 + js * 8];
                const float4* f1 = (const float4*)&fcw_lds[1][seg * 16 + js * 8];
                float4 a0 = f0[0], b0 = f0[1], a1 = f1[0], b1 = f1[1];
                p0 += (float)hv[0]*a0.x + (float)hv[1]*a0.y + (float)hv[2]*a0.z + (float)hv[3]*a0.w
                    + (float)hv[4]*b0.x + (float)hv[5]*b0.y + (float)hv[6]*b0.z + (float)hv[7]*b0.w;
                p1 += (float)hv[0]*a1.x + (float)hv[1]*a1.y + (float)hv[2]*a1.z + (float)hv[3]*a1.w
                    + (float)hv[4]*b1.x + (float)hv[5]*b1.y + (float)hv[6]*b1.z + (float)hv[7]*b1.w;
            }
            p0 += __shfl_xor(p0, 8); p0 += __shfl_xor(p0, 16); p0 += __shfl_xor(p0, 32);
            p1 += __shfl_xor(p1, 8); p1 += __shfl_xor(p1, 16); p1 += __shfl_xor(p1, 32);
            if (seg == 0) {
                float* op = &out[(size_t)(rb + r) * (2 * NFUT) + f * 2];
                op[0] = p0 + fcb0;
                op[1] = p1 + fcb1;
            }
        }
    };

    // ================= forecast: 50 steps ================
    for (int f = 0; f < NFUT; f += 2) {
        emitY(h_lds[0], f);
        cellF(h_lds[0], h_lds[1]);
        emitY(h_lds[1], f + 1);
        cellF(h_lds[1], h_lds[0]);
    }
}

extern "C" void kernel_launch(void* const* d_in, const int* in_sizes, int n_in,
                              void* d_out, int out_size, void* d_ws, size_t ws_size,
                              hipStream_t stream) {
    const float* x    = (const float*)d_in[0];
    const float* W_ih = (const float*)d_in[1];
    const float* W_hh = (const float*)d_in[2];
    const float* b_ih = (const float*)d_in[3];
    const float* b_hh = (const float*)d_in[4];
    const float* fc_w = (const float*)d_in[5];
    const float* fc_b = (const float*)d_in[6];
    float* out = (float*)d_out;

    const int B = in_sizes[0] / (TSTEPS * 2);   // 4096
    const int grid = B / BR;                    // 512 blocks -> 2 per CU
    lstm_forecast_kernel<<<grid, THREADS, 0, stream>>>(x, W_ih, W_hh, b_ih, b_hh, fc_w, fc_b, out);
}